// Round 5
// baseline (97.227 us; speedup 1.0000x reference)
//
#include <hip/hip_runtime.h>

#define IMG_W 1024
#define IMG_H 1024

// Packed 2 x f16: one VGPR holds the same window-position value for two
// horizontally adjacent output pixels. Inline asm guarantees single
// v_pk_min_f16 / v_pk_max_f16 per comparator half (clang's elementwise
// builtins may scalarize to 2x v_min_f16 + repack).
typedef _Float16 h2 __attribute__((ext_vector_type(2)));

__device__ __forceinline__ h2 mn(h2 a, h2 b) {
    h2 r; asm("v_pk_min_f16 %0, %1, %2" : "=v"(r) : "v"(a), "v"(b)); return r;
}
__device__ __forceinline__ h2 mx(h2 a, h2 b) {
    h2 r; asm("v_pk_max_f16 %0, %1, %2" : "=v"(r) : "v"(a), "v"(b)); return r;
}
__device__ __forceinline__ void ce(h2 &a, h2 &b) { h2 t = mn(a, b); b = mx(a, b); a = t; }
// median-of-3, packed (4 ops; case-verified for all orderings)
__device__ __forceinline__ h2 med3p(h2 a, h2 b, h2 c) {
    return mx(mn(a, b), mn(mx(a, b), c));
}
// 9-CE optimal sort5 (validated absmax=0 rounds 1-3, f16 round 4)
__device__ __forceinline__ void sort5(h2 &a0, h2 &a1, h2 &a2, h2 &a3, h2 &a4) {
    ce(a0, a1); ce(a3, a4); ce(a2, a4); ce(a2, a3);
    ce(a0, a3); ce(a0, a2); ce(a1, a4); ce(a1, a3); ce(a1, a2);
}
// 5-CE sort4
__device__ __forceinline__ void sort4(h2 &a, h2 &b, h2 &c, h2 &d) {
    ce(a, b); ce(c, d); ce(a, c); ce(b, d); ce(b, c);
}

__device__ __forceinline__ h2 bch2(unsigned u) { return __builtin_bit_cast(h2, u); }

// A sorted 5-wide horizontal window row (packed for 2 pixels).
struct Row { h2 a, b, c, d, e; };

// Load one tile row's 6 halfwords (3 dwords) and build + sort the 5 packed
// window values. Funnel shifts fuse to v_alignbit_b32.
__device__ __forceinline__ Row load_sort_row(const unsigned* __restrict__ ldsrow, int tx) {
    unsigned d0 = ldsrow[tx], d1 = ldsrow[tx + 1], d2 = ldsrow[tx + 2];
    h2 p0 = bch2(d0);
    h2 p1 = bch2((d0 >> 16) | (d1 << 16));
    h2 p2 = bch2(d1);
    h2 p3 = bch2((d1 >> 16) | (d2 << 16));
    h2 p4 = bch2(d2);
    sort5(p0, p1, p2, p3, p4);
    return {p0, p1, p2, p3, p4};
}

// Forgetful selection: median (rank 6) of the 13 candidates (validated net).
__device__ __forceinline__ h2 tail13(h2 A, h2 B, h2 c1a, h2 c1b, h2 c1c,
                                     h2 c2a, h2 c2b, h2 c2c,
                                     h2 c3a, h2 c3b, h2 c3c, h2 D, h2 E) {
    ce(A, D); ce(c1a, c3a); ce(A, c1a);        // A = min8 (drop)
    ce(B, E); ce(c1b, c3b); ce(E, c3b);        // c3b = max8 (drop)
    h2 e0 = B, e1 = D, e2 = E, e3 = c1a, e4 = c1b, e5 = c3a, e6 = c1c;
    ce(e0, e1); ce(e2, e3); ce(e4, e5);
    ce(e0, e2); ce(e4, e6); ce(e0, e4);        // e0 = min7 (drop)
    ce(e1, e3); ce(e5, e6); ce(e3, e6);        // e6 = max7 (drop)
    h2 f0 = e1, f1 = e2, f2 = e3, f3 = e4, f4 = e5, f5 = c2a;
    ce(f0, f1); ce(f2, f3); ce(f4, f5);
    ce(f0, f2); ce(f0, f4);                    // f0 = min6 (drop)
    ce(f1, f3); ce(f3, f5);                    // f5 = max6 (drop)
    h2 g0 = f1, g1 = f2, g2 = f3, g3 = f4, g4 = c2b;
    ce(g0, g1); ce(g2, g3);
    ce(g0, g2); ce(g0, g4);                    // g0 = min5 (drop)
    ce(g1, g3); ce(g3, g4);                    // g4 = max5 (drop)
    h2 h0 = g1, h1 = g2, h2_ = g3, h3 = c2c;
    ce(h0, h1); ce(h2_, h3); ce(h0, h2_); ce(h1, h3);
    return med3p(h1, h2_, c3c);
}

// Two vertically adjacent windows sharing 4 rows (rb..re); per column sort4
// the shared values once, then extract each window's candidates from
// sorted4 + its private row (ra = window-lo's extra row, rf = window-hi's).
// All extraction formulas case-verified (round 4, absmax 0.0078 = f16 ulp).
__device__ __forceinline__ void pair_medians(const Row &rb, const Row &rc, const Row &rd,
                                             const Row &re, const Row &ra, const Row &rf,
                                             h2 &out_lo, h2 &out_hi) {
    h2 s0, s1, s2, s3;
    // col0: candidate ranks {3,4} -> (A,B), A<=B
    s0 = rb.a; s1 = rc.a; s2 = rd.a; s3 = re.a; sort4(s0, s1, s2, s3);
    h2 Bl = mx(s3, ra.a), Al = mx(s2, mn(s3, ra.a));
    h2 Bh = mx(s3, rf.a), Ah = mx(s2, mn(s3, rf.a));
    // col1: top-3 set
    s0 = rb.b; s1 = rc.b; s2 = rd.b; s3 = re.b; sort4(s0, s1, s2, s3);
    h2 c1al = s2, c1bl = s3, c1cl = mx(s1, ra.b);
    h2 c1ah = s2, c1bh = s3, c1ch = mx(s1, rf.b);
    // col2: middle-3 set
    s0 = rb.c; s1 = rc.c; s2 = rd.c; s3 = re.c; sort4(s0, s1, s2, s3);
    h2 c2al = s1, c2bl = s2, c2cl = med3p(s0, ra.c, s3);
    h2 c2ah = s1, c2bh = s2, c2ch = med3p(s0, rf.c, s3);
    // col3: bottom-3 set
    s0 = rb.d; s1 = rc.d; s2 = rd.d; s3 = re.d; sort4(s0, s1, s2, s3);
    h2 c3al = s0, c3bl = s1, c3cl = mn(s2, ra.d);
    h2 c3ah = s0, c3bh = s1, c3ch = mn(s2, rf.d);
    // col4: candidate ranks {0,1} -> (D,E), D<=E
    s0 = rb.e; s1 = rc.e; s2 = rd.e; s3 = re.e; sort4(s0, s1, s2, s3);
    h2 Dl = mn(s0, ra.e), El = mn(s1, mx(s0, ra.e));
    h2 Dh = mn(s0, rf.e), Eh = mn(s1, mx(s0, rf.e));

    out_lo = tail13(Al, Bl, c1al, c1bl, c1cl, c2al, c2bl, c2cl, c3al, c3bl, c3cl, Dl, El);
    out_hi = tail13(Ah, Bh, c1ah, c1bh, c1ch, c2ah, c2bh, c2ch, c3ah, c3bh, c3ch, Dh, Eh);
}

// Block: 32x8 threads. Lane covers 2 adjacent output columns x 8 output rows
// (16 px/thread). Tile: 64x64 outputs, LDS 68 rows x 35 dwords (70 f16) = 9520 B.
#define LDS_DW 35
__global__ __launch_bounds__(256, 4) void median5x5_kernel(const float* __restrict__ x,
                                                           float* __restrict__ out) {
    __shared__ unsigned lds[68][LDS_DW];

    const int tx = threadIdx.x;          // 0..31
    const int ty = threadIdx.y;          // 0..7
    const int tid = ty * 32 + tx;
    const int plane = blockIdx.z;
    const float* src = x + (size_t)plane * IMG_H * IMG_W;

    const int gx0 = blockIdx.x * 64 - 2;   // halfword h maps input col gx0+h
    const int gy0 = blockIdx.y * 64 - 2;

    // Stage: f32 global -> packed f16 LDS (cvt_pkrtz; RTZ is monotone so the
    // selected median equals f16(true median), err <= ulp ~ 0.004 < 0.0264 tol).
    // Interior lanes: one dwordx2 load; border lanes: guarded scalar loads.
    for (unsigned idx = tid; idx < 68u * LDS_DW; idx += 256) {
        unsigned r = idx / LDS_DW;
        unsigned dc = idx - r * LDS_DW;
        int gy = gy0 + (int)r;
        int gxa = gx0 + 2 * (int)dc;
        bool rowok = (unsigned)gy < (unsigned)IMG_H;
        float a, b;
        if (rowok && gxa >= 0 && gxa + 1 < IMG_W) {
            float2 v2 = *reinterpret_cast<const float2*>(src + (size_t)gy * IMG_W + gxa);
            a = v2.x; b = v2.y;
        } else {
            a = (rowok && (unsigned)gxa < (unsigned)IMG_W) ? src[(size_t)gy * IMG_W + gxa] : 0.0f;
            b = (rowok && (unsigned)(gxa + 1) < (unsigned)IMG_W) ? src[(size_t)gy * IMG_W + gxa + 1] : 0.0f;
        }
        lds[r][dc] = __builtin_bit_cast(unsigned, __builtin_amdgcn_cvt_pkrtz(a, b));
    }
    __syncthreads();

    const int base = ty * 8;               // first output row (tile-local) of this thread
    // Rolling 6-row register window over tile rows base+0 .. base+11.
    Row S0 = load_sort_row(&lds[base + 0][0], tx);
    Row S1 = load_sort_row(&lds[base + 1][0], tx);
    Row S2 = load_sort_row(&lds[base + 2][0], tx);
    Row S3 = load_sort_row(&lds[base + 3][0], tx);
    Row S4 = load_sort_row(&lds[base + 4][0], tx);
    Row S5 = load_sort_row(&lds[base + 5][0], tx);

    float* dst = out + (size_t)plane * IMG_H * IMG_W
               + (size_t)(blockIdx.y * 64 + base) * IMG_W + blockIdx.x * 64 + 2 * tx;
    h2 mlo, mhi;

#define EMIT(vv, m) do {                                                       \
        float2 o; o.x = (float)(m).x; o.y = (float)(m).y;                      \
        *reinterpret_cast<float2*>(dst + (size_t)(vv) * IMG_W) = o;            \
    } while (0)

    // pair 0: windows rows 0-4 / 1-5 (shared 1-4)
    pair_medians(S1, S2, S3, S4, S0, S5, mlo, mhi);
    EMIT(0, mlo); EMIT(1, mhi);
    S0 = load_sort_row(&lds[base + 6][0], tx);
    S1 = load_sort_row(&lds[base + 7][0], tx);
    // pair 1: windows rows 2-6 / 3-7 (shared 3-6)
    pair_medians(S3, S4, S5, S0, S2, S1, mlo, mhi);
    EMIT(2, mlo); EMIT(3, mhi);
    S2 = load_sort_row(&lds[base + 8][0], tx);
    S3 = load_sort_row(&lds[base + 9][0], tx);
    // pair 2: windows rows 4-8 / 5-9 (shared 5-8)
    pair_medians(S5, S0, S1, S2, S4, S3, mlo, mhi);
    EMIT(4, mlo); EMIT(5, mhi);
    S4 = load_sort_row(&lds[base + 10][0], tx);
    S5 = load_sort_row(&lds[base + 11][0], tx);
    // pair 3: windows rows 6-10 / 7-11 (shared 7-10)
    pair_medians(S1, S2, S3, S4, S0, S5, mlo, mhi);
    EMIT(6, mlo); EMIT(7, mhi);
#undef EMIT
}

extern "C" void kernel_launch(void* const* d_in, const int* in_sizes, int n_in,
                              void* d_out, int out_size, void* d_ws, size_t ws_size,
                              hipStream_t stream) {
    const float* x = (const float*)d_in[0];
    float* out = (float*)d_out;
    const int planes = in_sizes[0] / (IMG_H * IMG_W);   // B*C = 8
    dim3 grid(IMG_W / 64, IMG_H / 64, planes);
    dim3 block(32, 8);
    median5x5_kernel<<<grid, block, 0, stream>>>(x, out);
}

// Round 6
// 90.295 us; speedup vs baseline: 1.0768x; 1.0768x over previous
//
#include <hip/hip_runtime.h>

#define IMG_W 1024
#define IMG_H 1024

// Packed 2 x f16: one VGPR holds the same window-position value for two
// horizontally adjacent output pixels; v_pk_min/max_f16 = 1 CE half for 2 px.
typedef _Float16 h2 __attribute__((ext_vector_type(2)));

__device__ __forceinline__ h2 mn(h2 a, h2 b) {
    h2 r; asm("v_pk_min_f16 %0, %1, %2" : "=v"(r) : "v"(a), "v"(b)); return r;
}
__device__ __forceinline__ h2 mx(h2 a, h2 b) {
    h2 r; asm("v_pk_max_f16 %0, %1, %2" : "=v"(r) : "v"(a), "v"(b)); return r;
}
__device__ __forceinline__ void ce(h2 &a, h2 &b) { h2 t = mn(a, b); b = mx(a, b); a = t; }
__device__ __forceinline__ h2 med3p(h2 a, h2 b, h2 c) {
    return mx(mn(a, b), mn(mx(a, b), c));
}
// 9-CE optimal sort5 (validated rounds 1-5)
__device__ __forceinline__ void sort5(h2 &a0, h2 &a1, h2 &a2, h2 &a3, h2 &a4) {
    ce(a0, a1); ce(a3, a4); ce(a2, a4); ce(a2, a3);
    ce(a0, a3); ce(a0, a2); ce(a1, a4); ce(a1, a3); ce(a1, a2);
}
// 5-CE sort4
__device__ __forceinline__ void sort4(h2 &a, h2 &b, h2 &c, h2 &d) {
    ce(a, b); ce(c, d); ce(a, c); ce(b, d); ce(b, c);
}

__device__ __forceinline__ h2 bch2(unsigned u) { return __builtin_bit_cast(h2, u); }

struct Row { h2 a, b, c, d, e; };     // sorted 5-wide window (packed 2 px)
struct Raw { unsigned d0, d1, d2; };  // 3 raw LDS dwords of one tile row

#define LDS_DW 35                      // dwords per tile row (70 f16 cols)
#define LDS_PAD 2560                   // 256 threads * 10 slots (>= 68*35=2380)

__device__ __forceinline__ Raw load_raw(const unsigned* __restrict__ ldsf, int row, int tx) {
    const unsigned* p = ldsf + row * LDS_DW + tx;
    Raw r; r.d0 = p[0]; r.d1 = p[1]; r.d2 = p[2];
    return r;
}
__device__ __forceinline__ Row sort_row(Raw r) {
    h2 p0 = bch2(r.d0);
    h2 p1 = bch2((r.d0 >> 16) | (r.d1 << 16));
    h2 p2 = bch2(r.d1);
    h2 p3 = bch2((r.d1 >> 16) | (r.d2 << 16));
    h2 p4 = bch2(r.d2);
    sort5(p0, p1, p2, p3, p4);
    return {p0, p1, p2, p3, p4};
}

// Forgetful selection: median (rank 6) of the 13 candidates (validated net).
__device__ __forceinline__ h2 tail13(h2 A, h2 B, h2 c1a, h2 c1b, h2 c1c,
                                     h2 c2a, h2 c2b, h2 c2c,
                                     h2 c3a, h2 c3b, h2 c3c, h2 D, h2 E) {
    ce(A, D); ce(c1a, c3a); ce(A, c1a);        // A = min8 (drop)
    ce(B, E); ce(c1b, c3b); ce(E, c3b);        // c3b = max8 (drop)
    h2 e0 = B, e1 = D, e2 = E, e3 = c1a, e4 = c1b, e5 = c3a, e6 = c1c;
    ce(e0, e1); ce(e2, e3); ce(e4, e5);
    ce(e0, e2); ce(e4, e6); ce(e0, e4);        // e0 = min7 (drop)
    ce(e1, e3); ce(e5, e6); ce(e3, e6);        // e6 = max7 (drop)
    h2 f0 = e1, f1 = e2, f2 = e3, f3 = e4, f4 = e5, f5 = c2a;
    ce(f0, f1); ce(f2, f3); ce(f4, f5);
    ce(f0, f2); ce(f0, f4);                    // f0 = min6 (drop)
    ce(f1, f3); ce(f3, f5);                    // f5 = max6 (drop)
    h2 g0 = f1, g1 = f2, g2 = f3, g3 = f4, g4 = c2b;
    ce(g0, g1); ce(g2, g3);
    ce(g0, g2); ce(g0, g4);                    // g0 = min5 (drop)
    ce(g1, g3); ce(g3, g4);                    // g4 = max5 (drop)
    h2 h0 = g1, h1 = g2, h2_ = g3, h3 = c2c;
    ce(h0, h1); ce(h2_, h3); ce(h0, h2_); ce(h1, h3);
    return med3p(h1, h2_, c3c);
}

// Two vertically adjacent windows sharing rows rb..re; sort4 shared column
// values once, extract both windows' candidates from sorted4 + private row
// (ra = lo's extra, rf = hi's). Validated round 4/5 (absmax = f16 ulp).
__device__ __forceinline__ void pair_medians(const Row &rb, const Row &rc, const Row &rd,
                                             const Row &re, const Row &ra, const Row &rf,
                                             h2 &out_lo, h2 &out_hi) {
    h2 s0, s1, s2, s3;
    s0 = rb.a; s1 = rc.a; s2 = rd.a; s3 = re.a; sort4(s0, s1, s2, s3);
    h2 Bl = mx(s3, ra.a), Al = mx(s2, mn(s3, ra.a));
    h2 Bh = mx(s3, rf.a), Ah = mx(s2, mn(s3, rf.a));
    s0 = rb.b; s1 = rc.b; s2 = rd.b; s3 = re.b; sort4(s0, s1, s2, s3);
    h2 c1al = s2, c1bl = s3, c1cl = mx(s1, ra.b);
    h2 c1ah = s2, c1bh = s3, c1ch = mx(s1, rf.b);
    s0 = rb.c; s1 = rc.c; s2 = rd.c; s3 = re.c; sort4(s0, s1, s2, s3);
    h2 c2al = s1, c2bl = s2, c2cl = med3p(s0, ra.c, s3);
    h2 c2ah = s1, c2bh = s2, c2ch = med3p(s0, rf.c, s3);
    s0 = rb.d; s1 = rc.d; s2 = rd.d; s3 = re.d; sort4(s0, s1, s2, s3);
    h2 c3al = s0, c3bl = s1, c3cl = mn(s2, ra.d);
    h2 c3ah = s0, c3bh = s1, c3ch = mn(s2, rf.d);
    s0 = rb.e; s1 = rc.e; s2 = rd.e; s3 = re.e; sort4(s0, s1, s2, s3);
    h2 Dl = mn(s0, ra.e), El = mn(s1, mx(s0, ra.e));
    h2 Dh = mn(s0, rf.e), Eh = mn(s1, mx(s0, rf.e));

    out_lo = tail13(Al, Bl, c1al, c1bl, c1cl, c2al, c2bl, c2cl, c3al, c3bl, c3cl, Dl, El);
    out_hi = tail13(Ah, Bh, c1ah, c1bh, c1ch, c2ah, c2bh, c2ch, c3ah, c3bh, c3ch, Dh, Eh);
}

// Block 32x8; lane = 2 cols x 16 px; tile 64x64 outputs.
__global__ __launch_bounds__(256, 4) void median5x5_kernel(const float* __restrict__ x,
                                                           float* __restrict__ out) {
    __shared__ unsigned ldsf[LDS_PAD];

    const int tx = threadIdx.x;          // 0..31
    const int ty = threadIdx.y;          // 0..7
    const int tid = ty * 32 + tx;
    const int plane = blockIdx.z;
    const float* src = x + (size_t)plane * IMG_H * IMG_W;

    const int gx0 = blockIdx.x * 64 - 2;   // halfword h <-> input col gx0+h
    const int gy0 = blockIdx.y * 64 - 2;

    // ---- Staging: ALL 10 loads issued before any ds_write consumes them ----
    // (fixes the rolled-loop vmcnt(0)-per-iteration serialization: ~900 cyc
    //  HBM latency exposed once, not 10x). Clamped addresses keep every load
    //  legal & unconditional; out-of-image lanes are zeroed post-load.
    float2 v[10];
    int oka[10], okb[10];
    #pragma unroll
    for (int k = 0; k < 10; ++k) {
        int idx = tid + k * 256;
        int r = idx / LDS_DW;                 // magic-mul; junk rows (>=68) land
        int dc = idx - r * LDS_DW;            // in LDS pad, never read back
        int gy = gy0 + r;
        int gxa = gx0 + 2 * dc;               // always even -> 8B aligned
        int cgy = min(max(gy, 0), IMG_H - 1);
        int cgx = min(max(gxa, 0), IMG_W - 2);
        v[k] = *reinterpret_cast<const float2*>(src + (size_t)cgy * IMG_W + cgx);
        oka[k] = ((unsigned)gy < IMG_H) & ((unsigned)gxa < IMG_W);
        okb[k] = ((unsigned)gy < IMG_H) & ((unsigned)(gxa + 1) < IMG_W);
    }
    #pragma unroll
    for (int k = 0; k < 10; ++k) {
        int idx = tid + k * 256;
        float a = oka[k] ? v[k].x : 0.0f;
        float b = okb[k] ? v[k].y : 0.0f;
        ldsf[idx] = __builtin_bit_cast(unsigned, __builtin_amdgcn_cvt_pkrtz(a, b));
    }
    __syncthreads();

    const int base = ty * 8;
    // Preload raw dwords for rows 0..5, then sort (ds_read latency amortized).
    Raw r0 = load_raw(ldsf, base + 0, tx), r1 = load_raw(ldsf, base + 1, tx),
        r2 = load_raw(ldsf, base + 2, tx), r3 = load_raw(ldsf, base + 3, tx),
        r4 = load_raw(ldsf, base + 4, tx), r5 = load_raw(ldsf, base + 5, tx);
    Row S0 = sort_row(r0), S1 = sort_row(r1), S2 = sort_row(r2),
        S3 = sort_row(r3), S4 = sort_row(r4), S5 = sort_row(r5);

    float* dst = out + (size_t)plane * IMG_H * IMG_W
               + (size_t)(blockIdx.y * 64 + base) * IMG_W + blockIdx.x * 64 + 2 * tx;
    h2 mlo, mhi;

#define EMIT(vv, m) do {                                                       \
        float2 o; o.x = (float)(m).x; o.y = (float)(m).y;                      \
        *reinterpret_cast<float2*>(dst + (size_t)(vv) * IMG_W) = o;            \
    } while (0)

    // Prefetch next pair's raw rows BEFORE each heavy compute block so the
    // 6 ds_reads' latency hides under ~190 VALU ops.
    Raw n0 = load_raw(ldsf, base + 6, tx), n1 = load_raw(ldsf, base + 7, tx);
    pair_medians(S1, S2, S3, S4, S0, S5, mlo, mhi);   // windows 0-4 / 1-5
    EMIT(0, mlo); EMIT(1, mhi);
    S0 = sort_row(n0); S1 = sort_row(n1);

    n0 = load_raw(ldsf, base + 8, tx); n1 = load_raw(ldsf, base + 9, tx);
    pair_medians(S3, S4, S5, S0, S2, S1, mlo, mhi);   // windows 2-6 / 3-7
    EMIT(2, mlo); EMIT(3, mhi);
    S2 = sort_row(n0); S3 = sort_row(n1);

    n0 = load_raw(ldsf, base + 10, tx); n1 = load_raw(ldsf, base + 11, tx);
    pair_medians(S5, S0, S1, S2, S4, S3, mlo, mhi);   // windows 4-8 / 5-9
    EMIT(4, mlo); EMIT(5, mhi);
    S4 = sort_row(n0); S5 = sort_row(n1);

    pair_medians(S1, S2, S3, S4, S0, S5, mlo, mhi);   // windows 6-10 / 7-11
    EMIT(6, mlo); EMIT(7, mhi);
#undef EMIT
}

extern "C" void kernel_launch(void* const* d_in, const int* in_sizes, int n_in,
                              void* d_out, int out_size, void* d_ws, size_t ws_size,
                              hipStream_t stream) {
    const float* x = (const float*)d_in[0];
    float* out = (float*)d_out;
    const int planes = in_sizes[0] / (IMG_H * IMG_W);   // B*C = 8
    dim3 grid(IMG_W / 64, IMG_H / 64, planes);
    dim3 block(32, 8);
    median5x5_kernel<<<grid, block, 0, stream>>>(x, out);
}